// Round 1
// baseline (40.626 us; speedup 1.0000x reference)
//
#include <hip/hip_runtime.h>

#define C_DIM 32
#define M_DIM 64
#define NG    8   // NGEN

// Kernel 1: one block, 512 threads = (m,g) pairs.
// Computes per-(m,g) tables: like, hval, hidx (as float), into d_ws.
__global__ void cgmm_tables(const float* __restrict__ B, const float* __restrict__ Pi,
                            float* __restrict__ tab) {
    __shared__ float lsePi_s[NG];
    __shared__ float lseB_s[C_DIM * NG];
    const int tid = threadIdx.x;

    if (tid < NG) {
        float mx = -1e30f;
        for (int c = 0; c < C_DIM; ++c) mx = fmaxf(mx, Pi[c * NG + tid]);
        float s = 0.f;
        for (int c = 0; c < C_DIM; ++c) s += __expf(Pi[c * NG + tid] - mx) * 0.f + expf(Pi[c * NG + tid] - mx);
        lsePi_s[tid] = logf(s) + mx;
    }
    if (tid < C_DIM * NG) {
        const int c = tid / NG, g = tid % NG;
        const float* base = B + (size_t)c * (M_DIM * NG) + g;
        float mx = -1e30f;
        for (int m = 0; m < M_DIM; ++m) mx = fmaxf(mx, base[m * NG]);
        float s = 0.f;
        for (int m = 0; m < M_DIM; ++m) s += expf(base[m * NG] - mx);
        lseB_s[tid] = logf(s) + mx;
    }
    __syncthreads();

    const int m = tid >> 3;      // 0..63
    const int g = tid & 7;       // 0..7
    const float lp = lsePi_s[g];

    float L[C_DIM];
    float best = -1e30f;
    int bidx = 0;
    #pragma unroll
    for (int c = 0; c < C_DIM; ++c) {
        float v = B[(size_t)c * (M_DIM * NG) + (size_t)m * NG + g] - lseB_s[c * NG + g]
                + Pi[c * NG + g] - lp;
        L[c] = v;
        if (v > best) { best = v; bidx = c; }   // strict > ascending c == first max
    }
    float sumExp = 0.f, likeAcc = 0.f;
    #pragma unroll
    for (int c = 0; c < C_DIM; ++c) {
        float e = expf(L[c] - best);
        sumExp += e;
        likeAcc += e * L[c];
    }
    const int idx = m * NG + g;
    tab[idx]                   = likeAcc / sumExp;  // like[m,g]
    tab[M_DIM * NG + idx]      = 1.f / sumExp;      // hval[m,g] = max posterior
    tab[2 * M_DIM * NG + idx]  = (float)bidx;       // hidx[m,g]
}

// Kernel 2: one 64-thread block per graph. batch is sorted, so each graph's
// nodes are a contiguous range found via binary search. Threads = 8 node
// slots x 8 gens. Writes h_vals / h_idx per node and a deterministic
// shuffle-reduced likelihood per (graph, gen). No atomics.
__global__ void cgmm_nodes(const int* __restrict__ x, const int* __restrict__ batch,
                           const float* __restrict__ tab,
                           float* __restrict__ out, int N, int G) {
    __shared__ float like_s[M_DIM * NG];
    __shared__ float hval_s[M_DIM * NG];
    __shared__ float hidx_s[M_DIM * NG];
    const int tid = threadIdx.x;
    for (int i = tid; i < M_DIM * NG; i += 64) {
        like_s[i] = tab[i];
        hval_s[i] = tab[M_DIM * NG + i];
        hidx_s[i] = tab[2 * M_DIM * NG + i];
    }
    __syncthreads();

    const int j = blockIdx.x;

    // lower_bound(batch, j)
    int lo = 0, hi = N;
    while (lo < hi) { int mid = (lo + hi) >> 1; if (batch[mid] < j) lo = mid + 1; else hi = mid; }
    const int start = lo;
    // lower_bound(batch, j+1)
    hi = N;
    while (lo < hi) { int mid = (lo + hi) >> 1; if (batch[mid] < j + 1) lo = mid + 1; else hi = mid; }
    const int end = lo;

    const int slot = tid >> 3;   // 0..7
    const int g    = tid & 7;    // 0..7

    float* out_hv = out + (size_t)G * NG;
    float* out_hi = out_hv + (size_t)N * NG;

    float acc = 0.f;
    for (int n = start + slot; n < end; n += 8) {
        const int xm = x[n];                       // broadcast within 8-lane group
        acc += like_s[xm * NG + g];
        out_hv[(size_t)n * NG + g] = hval_s[xm * NG + g];
        out_hi[(size_t)n * NG + g] = hidx_s[xm * NG + g];
    }
    // reduce over the 8 slots sharing the same g (lanes differ in bits 3..5)
    acc += __shfl_xor(acc, 8);
    acc += __shfl_xor(acc, 16);
    acc += __shfl_xor(acc, 32);
    if (tid < NG) out[(size_t)j * NG + tid] = acc;
}

extern "C" void kernel_launch(void* const* d_in, const int* in_sizes, int n_in,
                              void* d_out, int out_size, void* d_ws, size_t ws_size,
                              hipStream_t stream) {
    const float* B     = (const float*)d_in[0];   // (C, M, NG)
    const float* Pi    = (const float*)d_in[1];   // (C, NG)
    const int*   x     = (const int*)d_in[2];     // (N,)
    const int*   batch = (const int*)d_in[3];     // (N,) sorted
    const int N = in_sizes[2];
    const int G = (out_size - 2 * N * NG) / NG;   // out = [G*NG | N*NG | N*NG]

    float* tab = (float*)d_ws;                    // 3 * 512 floats = 6 KB

    cgmm_tables<<<1, 512, 0, stream>>>(B, Pi, tab);
    cgmm_nodes<<<G, 64, 0, stream>>>(x, batch, tab, (float*)d_out, N, G);
}

// Round 2
// 24.812 us; speedup vs baseline: 1.6373x; 1.6373x over previous
//
#include <hip/hip_runtime.h>

#define C_DIM 32
#define M_DIM 64
#define NG    8   // NGEN
#define TAB   (M_DIM * NG)   // 512 entries per table

// ---------------------------------------------------------------------------
// K1: one block, 512 threads = (m,g) pairs. Stages B (64 KB) + Pi into LDS
// with coalesced float4 loads, then computes per-(m,g) tables:
//   tab[0..511]       like[m,g]  = sum_c softmax(L)_c * L_c
//   tab[512..1023]    hval[m,g]  = max_c posterior
//   tab[1024..1535]   hidx[m,g]  = argmax_c posterior (as float)
// where L[c] = (B[c,m,g]-lseB[c,g]) + (Pi[c,g]-lsePi[g]) = log numerator.
// ---------------------------------------------------------------------------
__global__ void cgmm_tables(const float* __restrict__ B, const float* __restrict__ Pi,
                            float* __restrict__ tab) {
    __shared__ float Bs[C_DIM * M_DIM * NG];     // 16384 floats = 64 KB
    __shared__ float Pis[C_DIM * NG];
    __shared__ float lsePi_s[NG];
    __shared__ float lseB_s[C_DIM * NG];
    const int tid = threadIdx.x;

    // coalesced staging
    const float4* B4 = (const float4*)B;
    float4* Bs4 = (float4*)Bs;
    #pragma unroll
    for (int i = tid; i < (C_DIM * M_DIM * NG) / 4; i += 512) Bs4[i] = B4[i];
    for (int i = tid; i < C_DIM * NG; i += 512) Pis[i] = Pi[i];
    __syncthreads();

    if (tid < NG) {
        float mx = -1e30f;
        for (int c = 0; c < C_DIM; ++c) mx = fmaxf(mx, Pis[c * NG + tid]);
        float s = 0.f;
        for (int c = 0; c < C_DIM; ++c) s += expf(Pis[c * NG + tid] - mx);
        lsePi_s[tid] = logf(s) + mx;
    }
    if (tid < C_DIM * NG) {
        const int c = tid >> 3, g = tid & 7;
        float mx = -1e30f;
        for (int m = 0; m < M_DIM; ++m) mx = fmaxf(mx, Bs[c * (M_DIM * NG) + m * NG + g]);
        float s = 0.f;
        for (int m = 0; m < M_DIM; ++m) s += expf(Bs[c * (M_DIM * NG) + m * NG + g] - mx);
        lseB_s[tid] = logf(s) + mx;
    }
    __syncthreads();

    const int m = tid >> 3;      // 0..63
    const int g = tid & 7;       // 0..7
    const float lp = lsePi_s[g];

    float L[C_DIM];
    float best = -1e30f;
    int bidx = 0;
    #pragma unroll
    for (int c = 0; c < C_DIM; ++c) {
        float v = Bs[c * (M_DIM * NG) + m * NG + g] - lseB_s[c * NG + g]
                + Pis[c * NG + g] - lp;
        L[c] = v;
        if (v > best) { best = v; bidx = c; }   // strict > ascending c == first max
    }
    float sumExp = 0.f, likeAcc = 0.f;
    #pragma unroll
    for (int c = 0; c < C_DIM; ++c) {
        float e = expf(L[c] - best);
        sumExp += e;
        likeAcc += e * L[c];
    }
    const int idx = m * NG + g;
    tab[idx]           = likeAcc / sumExp;
    tab[TAB + idx]     = 1.f / sumExp;
    tab[2 * TAB + idx] = (float)bidx;
}

// ---------------------------------------------------------------------------
// K2: node-parallel. One thread per node: writes h_vals / h_idx as 2x float4
// (fully coalesced), and emits the graph-boundary array starts[0..G] so K3
// needs no binary search. Total boundary-fill loop work across all threads = G.
// ---------------------------------------------------------------------------
__global__ void cgmm_nodes(const int* __restrict__ x, const int* __restrict__ batch,
                           const float* __restrict__ tab,
                           float* __restrict__ out_hv, float* __restrict__ out_hi,
                           int* __restrict__ starts, int N, int G) {
    __shared__ float hval_s[TAB];
    __shared__ float hidx_s[TAB];
    const int tid = threadIdx.x;
    for (int i = tid; i < TAB; i += 256) {
        hval_s[i] = tab[TAB + i];
        hidx_s[i] = tab[2 * TAB + i];
    }
    __syncthreads();

    const int n = blockIdx.x * 256 + tid;
    if (n >= N) return;

    const int bn = batch[n];
    if (n == 0) {
        for (int j = 0; j <= bn; ++j) starts[j] = 0;
    } else {
        const int bp = batch[n - 1];
        for (int j = bp + 1; j <= bn; ++j) starts[j] = n;   // empty if bp==bn
    }
    if (n == N - 1) {
        for (int j = bn + 1; j <= G; ++j) starts[j] = N;
    }

    const int xm = x[n];
    float4 v0 = *(const float4*)&hval_s[xm * NG];
    float4 v1 = *(const float4*)&hval_s[xm * NG + 4];
    float4 i0 = *(const float4*)&hidx_s[xm * NG];
    float4 i1 = *(const float4*)&hidx_s[xm * NG + 4];
    float4* hv = (float4*)(out_hv + (size_t)n * NG);
    float4* hi = (float4*)(out_hi + (size_t)n * NG);
    hv[0] = v0; hv[1] = v1;
    hi[0] = i0; hi[1] = i1;
}

// ---------------------------------------------------------------------------
// K3: one 64-lane wave per graph (4 graphs per 256-thread block).
// Direct starts[] lookup, 8 node-slots x 8 gens, deterministic shuffle reduce.
// ---------------------------------------------------------------------------
__global__ void cgmm_like(const int* __restrict__ x, const int* __restrict__ starts,
                          const float* __restrict__ tab,
                          float* __restrict__ out, int G) {
    __shared__ float like_s[TAB];
    const int tid = threadIdx.x;
    for (int i = tid; i < TAB; i += 256) like_s[i] = tab[i];
    __syncthreads();

    const int j = blockIdx.x * 4 + (tid >> 6);
    if (j >= G) return;
    const int start = starts[j];
    const int end   = starts[j + 1];

    const int slot = (tid >> 3) & 7;
    const int g    = tid & 7;

    float acc = 0.f;
    for (int n = start + slot; n < end; n += 8) {
        acc += like_s[x[n] * NG + g];
    }
    acc += __shfl_xor(acc, 8);
    acc += __shfl_xor(acc, 16);
    acc += __shfl_xor(acc, 32);
    if ((tid & 63) < NG) out[(size_t)j * NG + g] = acc;
}

extern "C" void kernel_launch(void* const* d_in, const int* in_sizes, int n_in,
                              void* d_out, int out_size, void* d_ws, size_t ws_size,
                              hipStream_t stream) {
    const float* B     = (const float*)d_in[0];   // (C, M, NG)
    const float* Pi    = (const float*)d_in[1];   // (C, NG)
    const int*   x     = (const int*)d_in[2];     // (N,)
    const int*   batch = (const int*)d_in[3];     // (N,) sorted
    const int N = in_sizes[2];
    const int G = (out_size - 2 * N * NG) / NG;   // out = [G*NG | N*NG | N*NG]

    float* tab    = (float*)d_ws;                        // 1536 floats
    int*   starts = (int*)((char*)d_ws + 3 * TAB * 4);   // G+1 ints

    float* out_like = (float*)d_out;
    float* out_hv   = out_like + (size_t)G * NG;
    float* out_hi   = out_hv + (size_t)N * NG;

    cgmm_tables<<<1, 512, 0, stream>>>(B, Pi, tab);
    cgmm_nodes<<<(N + 255) / 256, 256, 0, stream>>>(x, batch, tab, out_hv, out_hi, starts, N, G);
    cgmm_like<<<(G + 3) / 4, 256, 0, stream>>>(x, starts, tab, out_like, G);
}